// Round 5
// baseline (126.435 us; speedup 1.0000x reference)
//
#include <hip/hip_runtime.h>
#include <math.h>

#define J 24
#define RES 128
#define DHW (RES*RES*RES)
#define NBINS 16384   // (z0<<7)|y0

__device__ __constant__ int PARENTS[J] = {-1,0,0,0,1,2,3,4,5,6,7,8,9,9,9,12,13,14,16,17,18,19,20,21};

// Compose two 3x4 affines: out = a @ b
__device__ inline void compose34(const float* a, const float* b, float* r) {
    for (int i = 0; i < 3; ++i) {
        float a0 = a[i*4+0], a1 = a[i*4+1], a2 = a[i*4+2], a3 = a[i*4+3];
        r[i*4+0] = a0*b[0] + a1*b[4] + a2*b[8];
        r[i*4+1] = a0*b[1] + a1*b[5] + a2*b[9];
        r[i*4+2] = a0*b[2] + a1*b[6] + a2*b[10];
        r[i*4+3] = a0*b[3] + a1*b[7] + a2*b[11] + a3;
    }
}

// Kernel 1: rel transforms (B=4, J=24, 3x4) -> ws. Slot 0 = cano, 1..4 = batches.
__global__ void tf_kernel(const float* __restrict__ poses,
                          const float* __restrict__ cano_pose,
                          const float* __restrict__ rest_joints,
                          float* __restrict__ rel_out) {
    __shared__ float M[5][J][12];
    __shared__ float relj[J][3];
    __shared__ float cinv[J][12];
    const int t = threadIdx.x;

    if (t < J) {
        int p = PARENTS[t];
        for (int k = 0; k < 3; ++k) {
            float v = rest_joints[t*3+k];
            if (p >= 0) v -= rest_joints[p*3+k];
            relj[t][k] = v;
        }
    }
    __syncthreads();

    for (int task = t; task < 5*J; task += blockDim.x) {
        int s = task / J, j = task % J;
        const float* rv = (s == 0) ? (cano_pose + j*3) : (poses + ((s-1)*J + j)*3);
        float rx = rv[0], ry = rv[1], rz = rv[2];
        float ang = sqrtf(rx*rx + ry*ry + rz*rz) + 1e-8f;
        float ax = rx/ang, ay = ry/ang, az = rz/ang;
        float s_ = sinf(ang), c_ = cosf(ang), ic = 1.0f - c_;
        float* m = M[s][j];
        m[0]  = 1.0f - ic*(ay*ay + az*az);
        m[1]  = -s_*az + ic*ax*ay;
        m[2]  =  s_*ay + ic*ax*az;
        m[3]  = relj[j][0];
        m[4]  =  s_*az + ic*ax*ay;
        m[5]  = 1.0f - ic*(ax*ax + az*az);
        m[6]  = -s_*ax + ic*ay*az;
        m[7]  = relj[j][1];
        m[8]  = -s_*ay + ic*ax*az;
        m[9]  =  s_*ax + ic*ay*az;
        m[10] = 1.0f - ic*(ax*ax + ay*ay);
        m[11] = relj[j][2];
    }
    __syncthreads();

    if (t < 5) {
        for (int i = 1; i < J; ++i) {
            int p = PARENTS[i];
            float r[12];
            compose34(M[t][p], M[t][i], r);
            for (int k = 0; k < 12; ++k) M[t][i][k] = r[k];
        }
    }
    __syncthreads();

    for (int task = t; task < 5*J; task += blockDim.x) {
        int s = task / J, j = task % J;
        float* m = M[s][j];
        float rjx = rest_joints[j*3], rjy = rest_joints[j*3+1], rjz = rest_joints[j*3+2];
        m[3]  -= m[0]*rjx + m[1]*rjy + m[2]*rjz;
        m[7]  -= m[4]*rjx + m[5]*rjy + m[6]*rjz;
        m[11] -= m[8]*rjx + m[9]*rjy + m[10]*rjz;
    }
    __syncthreads();

    if (t < J) {
        const float* m = M[0][t];
        float* ci = cinv[t];
        ci[0] = m[0]; ci[1] = m[4]; ci[2]  = m[8];
        ci[4] = m[1]; ci[5] = m[5]; ci[6]  = m[9];
        ci[8] = m[2]; ci[9] = m[6]; ci[10] = m[10];
        ci[3]  = -(ci[0]*m[3] + ci[1]*m[7] + ci[2]*m[11]);
        ci[7]  = -(ci[4]*m[3] + ci[5]*m[7] + ci[6]*m[11]);
        ci[11] = -(ci[8]*m[3] + ci[9]*m[7] + ci[10]*m[11]);
    }
    __syncthreads();

    for (int task = t; task < 4*J; task += blockDim.x) {
        int b = task / J, j = task % J;
        float r[12];
        compose34(M[b+1][j], cinv[j], r);
        for (int k = 0; k < 12; ++k) rel_out[(b*J + j)*12 + k] = r[k];
    }
}

// zero the histogram
__global__ void zero_kernel(unsigned int* __restrict__ p, int n) {
    int i = blockIdx.x * blockDim.x + threadIdx.x;
    if (i < n) p[i] = 0;
}

// shared coordinate math: point -> (x0,y0,z0, tx,ty,tz) for the main grid
__device__ inline void main_grid_coords(float vx, float vy, float vz,
                                        float bcx, float bcy, float bcz, float be,
                                        float& px, float& py, float& pz,
                                        int& x0, int& y0, int& z0,
                                        float& tx, float& ty, float& tz) {
    px = (vx - bcx) / be * 2.0f;
    py = (vy - bcy) / be * 2.0f;
    pz = (vz - bcz) / be * 2.0f;
    const float S = (float)RES;
    float fx = ((px + 1.0f) * S - 1.0f) * 0.5f;
    float fy = ((py + 1.0f) * S - 1.0f) * 0.5f;
    float fz = ((pz + 1.0f) * S - 1.0f) * 0.5f;
    fx = fminf(fmaxf(fx, 0.0f), S - 1.0f);
    fy = fminf(fmaxf(fy, 0.0f), S - 1.0f);
    fz = fminf(fmaxf(fz, 0.0f), S - 1.0f);
    float x0f = floorf(fx), y0f = floorf(fy), z0f = floorf(fz);
    tx = fx - x0f; ty = fy - y0f; tz = fz - z0f;
    x0 = (int)x0f; y0 = (int)y0f; z0 = (int)z0f;
}

// Kernel 2: per-point bin key + histogram
__global__ __launch_bounds__(256) void key_kernel(
    const float* __restrict__ verts,
    const float* __restrict__ bbox_extend, const float* __restrict__ bbox_center,
    unsigned int* __restrict__ keys, unsigned int* __restrict__ hist, int total) {
    int i = blockIdx.x * blockDim.x + threadIdx.x;
    if (i >= total) return;
    float vx = verts[(size_t)i*3+0], vy = verts[(size_t)i*3+1], vz = verts[(size_t)i*3+2];
    float px, py, pz, tx, ty, tz;
    int x0, y0, z0;
    main_grid_coords(vx, vy, vz, bbox_center[0], bbox_center[1], bbox_center[2],
                     bbox_extend[0], px, py, pz, x0, y0, z0, tx, ty, tz);
    unsigned int key = ((unsigned)z0 << 7) | (unsigned)y0;
    keys[i] = key;
    atomicAdd(&hist[key], 1u);
}

// Kernel 3: exclusive scan of 16384-bin histogram -> cursor (single block, 1024 thr)
__global__ __launch_bounds__(1024) void scan_kernel(
    const unsigned int* __restrict__ hist, unsigned int* __restrict__ cursor) {
    __shared__ unsigned int partial[1024];
    const int t = threadIdx.x;
    const int CHUNK = NBINS / 1024;   // 16
    unsigned int local[CHUNK];
    unsigned int s = 0;
    #pragma unroll
    for (int k = 0; k < CHUNK; ++k) { local[k] = s; s += hist[t*CHUNK + k]; }
    partial[t] = s;
    __syncthreads();
    for (int off = 1; off < 1024; off <<= 1) {
        unsigned int v = (t >= off) ? partial[t - off] : 0u;
        __syncthreads();
        partial[t] += v;
        __syncthreads();
    }
    unsigned int excl = partial[t] - s;
    #pragma unroll
    for (int k = 0; k < CHUNK; ++k) cursor[t*CHUNK + k] = excl + local[k];
}

// Kernel 4: scatter point ids into bin order
__global__ __launch_bounds__(256) void scatter_kernel(
    const unsigned int* __restrict__ keys, unsigned int* __restrict__ cursor,
    unsigned int* __restrict__ order, int total) {
    int i = blockIdx.x * blockDim.x + threadIdx.x;
    if (i >= total) return;
    unsigned int key = keys[i];
    unsigned int pos = atomicAdd(&cursor[key], 1u);
    order[pos] = (unsigned int)i;
}

// f32 original-layout trilinear sample (hand grids; rare & clustered post-sort)
__device__ inline void sample_grid_f32(const float* __restrict__ g,
                                       float cx, float cy, float cz, float* w) {
    const float S = (float)RES;
    float fx = ((cx + 1.0f) * S - 1.0f) * 0.5f;
    float fy = ((cy + 1.0f) * S - 1.0f) * 0.5f;
    float fz = ((cz + 1.0f) * S - 1.0f) * 0.5f;
    fx = fminf(fmaxf(fx, 0.0f), S - 1.0f);
    fy = fminf(fmaxf(fy, 0.0f), S - 1.0f);
    fz = fminf(fmaxf(fz, 0.0f), S - 1.0f);
    float x0f = floorf(fx), y0f = floorf(fy), z0f = floorf(fz);
    float tx = fx - x0f, ty = fy - y0f, tz = fz - z0f;
    int x0 = (int)x0f, y0 = (int)y0f, z0 = (int)z0f;
    int x1 = x0 < RES-1 ? x0+1 : RES-1;
    int y1 = y0 < RES-1 ? y0+1 : RES-1;
    int z1 = z0 < RES-1 ? z0+1 : RES-1;
    int b00 = (z0*RES + y0)*RES;
    int b01 = (z0*RES + y1)*RES;
    int b10 = (z1*RES + y0)*RES;
    int b11 = (z1*RES + y1)*RES;
    float wx0 = 1.0f - tx, wx1 = tx;
    float wy0 = 1.0f - ty, wy1 = ty;
    float wz0 = 1.0f - tz, wz1 = tz;
    float w000 = wz0*wy0*wx0, w001 = wz0*wy0*wx1;
    float w010 = wz0*wy1*wx0, w011 = wz0*wy1*wx1;
    float w100 = wz1*wy0*wx0, w101 = wz1*wy0*wx1;
    float w110 = wz1*wy1*wx0, w111 = wz1*wy1*wx1;
    #pragma unroll
    for (int c = 0; c < J; ++c) {
        const float* gc = g + (size_t)c * DHW;
        w[c] = gc[b00+x0]*w000 + gc[b00+x1]*w001
             + gc[b01+x0]*w010 + gc[b01+x1]*w011
             + gc[b10+x0]*w100 + gc[b10+x1]*w101
             + gc[b11+x0]*w110 + gc[b11+x1]*w111;
    }
}

// Kernel 5: skin in sorted order — direct f32 gather from original-layout grid
__global__ __launch_bounds__(256) void skin_sorted(
    const float* __restrict__ verts,
    const float* __restrict__ wgrid,
    const float* __restrict__ lgrid,
    const float* __restrict__ rgrid,
    const float* __restrict__ rel,
    const unsigned int* __restrict__ order,
    const float* __restrict__ bbox_extend, const float* __restrict__ bbox_center,
    const float* __restrict__ lhand_extend, const float* __restrict__ lhand_center,
    const float* __restrict__ rhand_extend, const float* __restrict__ rhand_center,
    float* __restrict__ out, int N, int total) {
    __shared__ float srel[4*J*12];   // all 4 batches
    for (int i = threadIdx.x; i < 4*J*12; i += blockDim.x)
        srel[i] = rel[i];
    __syncthreads();

    int sid = blockIdx.x * blockDim.x + threadIdx.x;
    if (sid >= total) return;
    int pid = (int)order[sid];
    int b = pid / N;

    float vx = verts[(size_t)pid*3 + 0];
    float vy = verts[(size_t)pid*3 + 1];
    float vz = verts[(size_t)pid*3 + 2];

    float px, py, pz, tx, ty, tz;
    int x0, y0, z0;
    main_grid_coords(vx, vy, vz, bbox_center[0], bbox_center[1], bbox_center[2],
                     bbox_extend[0], px, py, pz, x0, y0, z0, tx, ty, tz);
    int x1 = x0 < RES-1 ? x0+1 : RES-1;
    int y1 = y0 < RES-1 ? y0+1 : RES-1;
    int z1 = z0 < RES-1 ? z0+1 : RES-1;
    int b00 = (z0*RES + y0)*RES;
    int b01 = (z0*RES + y1)*RES;
    int b10 = (z1*RES + y0)*RES;
    int b11 = (z1*RES + y1)*RES;
    float wx0 = 1.0f - tx, wx1 = tx;
    float wy0 = 1.0f - ty, wy1 = ty;
    float wz0 = 1.0f - tz, wz1 = tz;
    float w000 = wz0*wy0*wx0, w001 = wz0*wy0*wx1;
    float w010 = wz0*wy1*wx0, w011 = wz0*wy1*wx1;
    float w100 = wz1*wy0*wx0, w101 = wz1*wy0*wx1;
    float w110 = wz1*wy1*wx0, w111 = wz1*wy1*wx1;

    float w[J];
    #pragma unroll
    for (int c = 0; c < J; ++c) {
        const float* gc = wgrid + (size_t)c * DHW;
        w[c] = gc[b00+x0]*w000 + gc[b00+x1]*w001
             + gc[b01+x0]*w010 + gc[b01+x1]*w011
             + gc[b10+x0]*w100 + gc[b10+x1]*w101
             + gc[b11+x0]*w110 + gc[b11+x1]*w111;
    }

    // hand overrides (clustered by the sort -> mostly wave-uniform)
    float le = lhand_extend[0];
    float plx = px*le + lhand_center[0];
    float ply = py*le + lhand_center[1];
    float plz = pz*le + lhand_center[2];
    if (plx >= -1.0f && plx <= 1.0f && ply >= -1.0f && ply <= 1.0f &&
        plz >= -1.0f && plz <= 1.0f) {
        sample_grid_f32(lgrid, plx, ply, plz, w);
    }
    float re = rhand_extend[0];
    float prx = px*re + rhand_center[0];
    float pry = py*re + rhand_center[1];
    float prz = pz*re + rhand_center[2];
    if (prx >= -1.0f && prx <= 1.0f && pry >= -1.0f && pry <= 1.0f &&
        prz >= -1.0f && prz <= 1.0f) {
        sample_grid_f32(rgrid, prx, pry, prz, w);
    }

    // blend: M = sum_j w[j] * rel[b][j]
    const float* rb = &srel[b*J*12];
    float m[12];
    #pragma unroll
    for (int k = 0; k < 12; ++k) m[k] = 0.0f;
    #pragma unroll
    for (int j = 0; j < J; ++j) {
        float wj = w[j];
        const float* rj = &rb[j*12];
        #pragma unroll
        for (int k = 0; k < 12; ++k) m[k] += wj * rj[k];
    }

    out[(size_t)pid*3 + 0] = m[0]*vx + m[1]*vy + m[2]*vz  + m[3];
    out[(size_t)pid*3 + 1] = m[4]*vx + m[5]*vy + m[6]*vz  + m[7];
    out[(size_t)pid*3 + 2] = m[8]*vx + m[9]*vy + m[10]*vz + m[11];
}

extern "C" void kernel_launch(void* const* d_in, const int* in_sizes, int n_in,
                              void* d_out, int out_size, void* d_ws, size_t ws_size,
                              hipStream_t stream) {
    const float* verts       = (const float*)d_in[0];
    const float* poses       = (const float*)d_in[1];
    const float* cano_pose   = (const float*)d_in[2];
    const float* rest_joints = (const float*)d_in[3];
    const float* wgrid       = (const float*)d_in[4];
    const float* lgrid       = (const float*)d_in[5];
    const float* rgrid       = (const float*)d_in[6];
    const float* bbox_extend = (const float*)d_in[7];
    const float* bbox_center = (const float*)d_in[8];
    const float* lhand_extend= (const float*)d_in[9];
    const float* lhand_center= (const float*)d_in[10];
    const float* rhand_extend= (const float*)d_in[11];
    const float* rhand_center= (const float*)d_in[12];

    float* out = (float*)d_out;

    const int B = 4;
    const int total = in_sizes[0] / 3;
    const int N = total / B;

    // workspace layout
    char* ws = (char*)d_ws;
    float*        rel    = (float*)(ws);                       // 4608 B
    unsigned int* hist   = (unsigned int*)(ws + 8192);         // 64 KB
    unsigned int* cursor = (unsigned int*)(ws + 8192 + 65536); // 64 KB
    unsigned int* keys   = (unsigned int*)(ws + 8192 + 2*65536);           // total*4
    unsigned int* order  = (unsigned int*)(ws + 8192 + 2*65536 + (size_t)total*4);

    const int block = 256;
    const int pgrid = (total + block - 1) / block;

    tf_kernel<<<1, 128, 0, stream>>>(poses, cano_pose, rest_joints, rel);
    zero_kernel<<<(NBINS + block - 1) / block, block, 0, stream>>>(hist, NBINS);
    key_kernel<<<pgrid, block, 0, stream>>>(verts, bbox_extend, bbox_center,
                                            keys, hist, total);
    scan_kernel<<<1, 1024, 0, stream>>>(hist, cursor);
    scatter_kernel<<<pgrid, block, 0, stream>>>(keys, cursor, order, total);
    skin_sorted<<<pgrid, block, 0, stream>>>(
        verts, wgrid, lgrid, rgrid, rel, order,
        bbox_extend, bbox_center, lhand_extend, lhand_center,
        rhand_extend, rhand_center, out, N, total);
}